// Round 9
// baseline (1603.252 us; speedup 1.0000x reference)
//
#include <hip/hip_runtime.h>
#include <math.h>

// Problem constants
#define N_ROWS   131072      // 32*64*64 pixels
#define DIM      64          // embedding dim
#define KCODES   1024        // codebook entries
#define HWSZ     4096        // 64*64
#define CHW      262144      // 64*64*64 (per-batch NCHW stride)
#define OUT_ELEMS 8388608    // 32*64*64*64
#define BLOCK    128         // 2 waves/block, 1 wave/SIMD -> 512-reg budget
#define PIX      4           // pixels per thread: halves wave-wide fills vs P=2
#define PIXBLK   (BLOCK * PIX)        // 512 pixels per block
#define NBLOCKS  (N_ROWS / PIXBLK)    // 256 -> exactly 1 block/CU
#define TILE_K   128         // codes per LDS tile (32 KB)

typedef float v2f __attribute__((ext_vector_type(2)));

// packed fma: two pixel chains advance one d with one v_pk_fma_f32.
// Each component is an independent exact IEEE fp32 fma chain -> bit-identical.
__device__ __forceinline__ v2f fma2(v2f a, float b, v2f c) {
#if __has_builtin(__builtin_elementwise_fma)
    v2f bb = {b, b};
    return __builtin_elementwise_fma(a, bb, c);
#else
    v2f r;
    r[0] = __builtin_fmaf(a[0], b, c[0]);
    r[1] = __builtin_fmaf(a[1], b, c[1]);
    return r;
#endif
}

// ---------------------------------------------------------------------------
// numpy pairwise sum of squares, n=64 (8-accumulator block, scalar order).
// Bit-exact np.sum(v**2, axis=-1); contract(off) keeps mul/add separate.
// ---------------------------------------------------------------------------
__device__ __forceinline__ float np_sumsq64(const float* v) {
#pragma clang fp contract(off)
    float r[8];
#pragma unroll
    for (int j = 0; j < 8; ++j) r[j] = v[j] * v[j];
#pragma unroll
    for (int i = 8; i < 64; i += 8) {
#pragma unroll
        for (int j = 0; j < 8; ++j) {
            float p = v[i + j] * v[i + j];
            r[j] = r[j] + p;
        }
    }
    float s01 = r[0] + r[1];
    float s23 = r[2] + r[3];
    float s45 = r[4] + r[5];
    float s67 = r[6] + r[7];
    return (s01 + s23) + (s45 + s67);
}

// Same value sequence over component `comp` (LITERAL 0/1 at every callsite —
// constant extract_element only, no pointer cast: r5's spill trap avoided).
__device__ __forceinline__ float np_sumsq64_v2(const v2f* v, const int comp) {
#pragma clang fp contract(off)
    float r[8];
#pragma unroll
    for (int j = 0; j < 8; ++j) {
        const float t = v[j][comp];
        r[j] = t * t;
    }
#pragma unroll
    for (int i = 8; i < 64; i += 8) {
#pragma unroll
        for (int j = 0; j < 8; ++j) {
            const float t = v[i + j][comp];
            const float p = t * t;
            r[j] = r[j] + p;
        }
    }
    float s01 = r[0] + r[1];
    float s23 = r[2] + r[3];
    float s45 = r[4] + r[5];
    float s67 = r[6] + r[7];
    return (s01 + s23) + (s45 + s67);
}

// ---------------------------------------------------------------------------
// Kernel 0: per-code ||w_k||^2 (numpy-pairwise) -> ws[0..1023]
// ---------------------------------------------------------------------------
__global__ __launch_bounds__(256) void vq_wsum(const float* __restrict__ w,
                                               float* __restrict__ wsum) {
    int k = blockIdx.x * blockDim.x + threadIdx.x;   // grid = 4*256 = 1024
    const float* wr = w + k * DIM;
    float wv[DIM];
#pragma unroll
    for (int d = 0; d < DIM; ++d) wv[d] = wr[d];
    wsum[k] = np_sumsq64(wv);
}

// ---------------------------------------------------------------------------
// d-quarter helpers: 16 dims of a code pair in 8 float4 regs.
// ---------------------------------------------------------------------------
__device__ __forceinline__ void loadq(const float4* __restrict__ swv,
                                      int kka, int kkb, int q,
                                      float4 (&r0)[4], float4 (&r1)[4]) {
#pragma unroll
    for (int j = 0; j < 4; ++j) {
        r0[j] = swv[kka * 16 + q * 4 + j];
        r1[j] = swv[kkb * 16 + q * 4 + j];
    }
}

// fma over 16 dims (db..db+15): 2 codes x 4 pixels (2 v2f pairs).
// Per-(pixel,code) accumulation is d-ascending; quarters consumed in order
// db = 0,16,32,48 -> BIT-IDENTICAL to the sequential d=0..63 fmaf chain.
__device__ __forceinline__ void fma16p(const float4 (&ra)[4], const float4 (&rb)[4],
                                       const v2f* __restrict__ xp01,
                                       const v2f* __restrict__ xp23, int db,
                                       v2f& c0a, v2f& c0b, v2f& c1a, v2f& c1b) {
#pragma unroll
    for (int j = 0; j < 4; ++j) {
        const float4 va = ra[j];
        const float4 vb = rb[j];
        const int d = db + j * 4;
        c0a = fma2(xp01[d + 0], va.x, c0a);  c0b = fma2(xp23[d + 0], va.x, c0b);
        c1a = fma2(xp01[d + 0], vb.x, c1a);  c1b = fma2(xp23[d + 0], vb.x, c1b);
        c0a = fma2(xp01[d + 1], va.y, c0a);  c0b = fma2(xp23[d + 1], va.y, c0b);
        c1a = fma2(xp01[d + 1], vb.y, c1a);  c1b = fma2(xp23[d + 1], vb.y, c1b);
        c0a = fma2(xp01[d + 2], va.z, c0a);  c0b = fma2(xp23[d + 2], va.z, c0b);
        c1a = fma2(xp01[d + 2], vb.z, c1a);  c1b = fma2(xp23[d + 2], vb.z, c1b);
        c0a = fma2(xp01[d + 3], va.w, c0a);  c0b = fma2(xp23[d + 3], va.w, c0b);
        c1a = fma2(xp01[d + 3], vb.w, c1a);  c1b = fma2(xp23[d + 3], vb.w, c1b);
    }
}

// ---------------------------------------------------------------------------
// Kernel 1: main VQ — 4 pixels/thread (fill-law halving).
//   Session law (r3/r6/r8): weight delivery costs ~10 cyc per wave-wide
//   16B/lane register fill, summed per CU, REGARDLESS of pipe (LDS or L1).
//   Wall = 655K cyc / P. P=2 was the 267-297 us plateau; P=4 -> ~136 us.
//   - 128-thr blocks, 1 wave/SIMD (__launch_bounds__(128,1)): 512-reg
//     unified VGPR+AGPR budget holds x[4][64]=256 floats (r3 proved clean
//     AGPR residency; gfx90a+ VALU reads AGPRs directly).
//   - pixel pairs packed v2f -> v_pk_fma_f32: 256 pk-fma/body (512 issue-cyc)
//     stays under the 640-cyc/body fill budget. Components are exact fp32
//     fma chains; v2f indexed ONLY with literal components (no casts).
//   - no split-K: each thread sweeps codes 0..1023 ascending, strict <.
//   - single 32 KB tile, synchronous r3-style staging, LINEAR writes
//     (r8's 327K bank conflicts were stride-40 staging writes).
//   - d-quarter A/B register pipeline covers ds_read latency at 1 wave/SIMD.
//   Numerics BIT-IDENTICAL per (pixel, code):
//     a  = np_sumsq64(x);  c = sequential fmaf chain d=0..63
//     dk = fl( fl(a+b_k) - 2*c ),  argmin strict < (ascending code order)
// ---------------------------------------------------------------------------
__global__ __launch_bounds__(128, 1) void vq_main(const float* __restrict__ inp,
                                                  const float* __restrict__ weight,
                                                  const float* __restrict__ wsum,
                                                  float* __restrict__ out,
                                                  float* __restrict__ idx_out,
                                                  float* __restrict__ block_loss) {
    __shared__ float sw[TILE_K * DIM];   // 32 KB weight tile
    __shared__ float sws[TILE_K];        // wsum tile
    __shared__ float red[BLOCK / 64];

    const int tid = threadIdx.x;
    const int n0  = blockIdx.x * PIXBLK + tid;   // 4 pixels: +0,+128,+256,+384
    const int n1  = n0 + BLOCK;
    const int n2  = n1 + BLOCK;
    const int n3  = n2 + BLOCK;
    const int b0 = n0 >> 12, hw0 = n0 & 4095;
    const int b1 = n1 >> 12, hw1 = n1 & 4095;
    const int b2 = n2 >> 12, hw2 = n2 & 4095;
    const int b3 = n3 >> 12, hw3 = n3 & 4095;

    const float* xb0 = inp + (size_t)b0 * CHW + hw0;
    const float* xb1 = inp + (size_t)b1 * CHW + hw1;
    const float* xb2 = inp + (size_t)b2 * CHW + hw2;
    const float* xb3 = inp + (size_t)b3 * CHW + hw3;

    v2f xp01[DIM], xp23[DIM];
#pragma unroll
    for (int d = 0; d < DIM; ++d) {
        v2f u, v;
        u[0] = xb0[(size_t)d * HWSZ];
        u[1] = xb1[(size_t)d * HWSZ];
        v[0] = xb2[(size_t)d * HWSZ];
        v[1] = xb3[(size_t)d * HWSZ];
        xp01[d] = u;
        xp23[d] = v;
    }

    const float a0 = np_sumsq64_v2(xp01, 0);
    const float a1 = np_sumsq64_v2(xp01, 1);
    const float a2 = np_sumsq64_v2(xp23, 0);
    const float a3 = np_sumsq64_v2(xp23, 1);

    float bv0 = 3.402823466e38f, bv1 = 3.402823466e38f;
    float bv2 = 3.402823466e38f, bv3 = 3.402823466e38f;
    int   bk0 = 0, bk1 = 0, bk2 = 0, bk3 = 0;

    for (int tile = 0; tile < KCODES; tile += TILE_K) {
        // ---- stage tile: 128 codes x 64 floats, LINEAR (conflict-free) ----
        __syncthreads();   // protect previous tile's readers
        {
            const float4* gsrc = (const float4*)(weight + (size_t)tile * DIM);
            float4* ldst = (float4*)sw;
            // 8192 floats = 2048 float4; 128 threads -> 16 each
#pragma unroll
            for (int i = 0; i < 16; ++i)
                ldst[i * BLOCK + tid] = gsrc[i * BLOCK + tid];
            sws[tid] = wsum[tile + tid];
        }
        __syncthreads();

        const float4* swv = (const float4*)sw;

        // ---- sweep tile: 2 codes x 4 pixels, d-quarter A/B pipeline ----
        float4 A0[4], A1[4], B0[4], B1[4];
        loadq(swv, 0, 1, 0, A0, A1);   // preload quarter 0 of pair (0,1)

#pragma unroll 1
        for (int kk = 0; kk < TILE_K; kk += 2) {
            const int nk = (kk + 2 < TILE_K) ? (kk + 2) : 0;  // wrap (harmless)
            const float bsw0 = sws[kk];
            const float bsw1 = sws[kk + 1];
            v2f c0a = {0.f, 0.f}, c0b = {0.f, 0.f};
            v2f c1a = {0.f, 0.f}, c1b = {0.f, 0.f};

            loadq(swv, kk, kk + 1, 1, B0, B1);   // prefetch q1
            fma16p(A0, A1, xp01, xp23, 0,  c0a, c0b, c1a, c1b);
            loadq(swv, kk, kk + 1, 2, A0, A1);   // prefetch q2
            fma16p(B0, B1, xp01, xp23, 16, c0a, c0b, c1a, c1b);
            loadq(swv, kk, kk + 1, 3, B0, B1);   // prefetch q3
            fma16p(A0, A1, xp01, xp23, 32, c0a, c0b, c1a, c1b);
            loadq(swv, nk, nk + 1, 0, A0, A1);   // prefetch next pair q0
            fma16p(B0, B1, xp01, xp23, 48, c0a, c0b, c1a, c1b);

            float dk00, dk01, dk02, dk03, dk10, dk11, dk12, dk13;
            {
#pragma clang fp contract(off)
                const float s00 = a0 + bsw0;
                const float s01 = a1 + bsw0;
                const float s02 = a2 + bsw0;
                const float s03 = a3 + bsw0;
                const float s10 = a0 + bsw1;
                const float s11 = a1 + bsw1;
                const float s12 = a2 + bsw1;
                const float s13 = a3 + bsw1;
                dk00 = s00 - 2.0f * c0a[0];
                dk01 = s01 - 2.0f * c0a[1];
                dk02 = s02 - 2.0f * c0b[0];
                dk03 = s03 - 2.0f * c0b[1];
                dk10 = s10 - 2.0f * c1a[0];
                dk11 = s11 - 2.0f * c1a[1];
                dk12 = s12 - 2.0f * c1b[0];
                dk13 = s13 - 2.0f * c1b[1];
            }
            const int k0 = tile + kk;
            const int k1 = k0 + 1;
            if (dk00 < bv0) { bv0 = dk00; bk0 = k0; }
            if (dk10 < bv0) { bv0 = dk10; bk0 = k1; }
            if (dk01 < bv1) { bv1 = dk01; bk1 = k0; }
            if (dk11 < bv1) { bv1 = dk11; bk1 = k1; }
            if (dk02 < bv2) { bv2 = dk02; bk2 = k0; }
            if (dk12 < bv2) { bv2 = dk12; bk2 = k1; }
            if (dk03 < bv3) { bv3 = dk03; bk3 = k0; }
            if (dk13 < bv3) { bv3 = dk13; bk3 = k1; }
        }
    }

    // Epilogue: gather winning code rows, write out (coalesced), loss partial.
    const float* wb0 = weight + bk0 * DIM;   // per-lane gather, L2-hot
    const float* wb1 = weight + bk1 * DIM;
    const float* wb2 = weight + bk2 * DIM;
    const float* wb3 = weight + bk3 * DIM;
    float* ob0 = out + (size_t)b0 * CHW + hw0;
    float* ob1 = out + (size_t)b1 * CHW + hw1;
    float* ob2 = out + (size_t)b2 * CHW + hw2;
    float* ob3 = out + (size_t)b3 * CHW + hw3;
    float ls = 0.f;
#pragma unroll
    for (int c = 0; c < DIM; ++c) {
        const float w0 = wb0[c];
        ob0[(size_t)c * HWSZ] = w0;
        const float d0 = w0 - xp01[c][0];
        ls = fmaf(d0, d0, ls);
        const float w1 = wb1[c];
        ob1[(size_t)c * HWSZ] = w1;
        const float d1 = w1 - xp01[c][1];
        ls = fmaf(d1, d1, ls);
        const float w2 = wb2[c];
        ob2[(size_t)c * HWSZ] = w2;
        const float d2 = w2 - xp23[c][0];
        ls = fmaf(d2, d2, ls);
        const float w3 = wb3[c];
        ob3[(size_t)c * HWSZ] = w3;
        const float d3 = w3 - xp23[c][1];
        ls = fmaf(d3, d3, ls);
    }
    idx_out[n0] = (float)bk0;
    idx_out[n1] = (float)bk1;
    idx_out[n2] = (float)bk2;
    idx_out[n3] = (float)bk3;

    // Block reduction of loss partial (2 waves of 64)
#pragma unroll
    for (int off = 32; off > 0; off >>= 1) ls += __shfl_down(ls, off, 64);
    const int lane = tid & 63;
    const int wid  = tid >> 6;
    if (lane == 0) red[wid] = ls;
    __syncthreads();
    if (tid == 0)
        block_loss[blockIdx.x] = red[0] + red[1];
}

// ---------------------------------------------------------------------------
// Kernel 2: reduce 256 block partials -> loss scalar
//   loss = q + 0.25*e = 1.25 * mean((quantized - x)^2)
// ---------------------------------------------------------------------------
__global__ __launch_bounds__(256) void vq_loss_reduce(const float* __restrict__ bl,
                                                      float* __restrict__ loss_out) {
    double s = 0.0;
    for (int i = threadIdx.x; i < NBLOCKS; i += 256) s += (double)bl[i];
    __shared__ double red[4];
#pragma unroll
    for (int off = 32; off > 0; off >>= 1) s += __shfl_down(s, off, 64);
    const int lane = threadIdx.x & 63;
    const int wid  = threadIdx.x >> 6;
    if (lane == 0) red[wid] = s;
    __syncthreads();
    if (threadIdx.x == 0) {
        const double total = (red[0] + red[1]) + (red[2] + red[3]);
        loss_out[0] = (float)(1.25 * total / (double)OUT_ELEMS);
    }
}

// ---------------------------------------------------------------------------
extern "C" void kernel_launch(void* const* d_in, const int* in_sizes, int n_in,
                              void* d_out, int out_size, void* d_ws, size_t ws_size,
                              hipStream_t stream) {
    const float* inp    = (const float*)d_in[0];   // [32,64,64,64] NCHW fp32
    const float* weight = (const float*)d_in[1];   // [1024,64] fp32

    float* out_q    = (float*)d_out;                         // 8388608 elems
    float* out_loss = (float*)d_out + OUT_ELEMS;             // 1 elem
    float* out_idx  = (float*)d_out + OUT_ELEMS + 1;         // 131072 elems

    float* wsum       = (float*)d_ws;                        // 1024 floats
    float* block_loss = (float*)d_ws + KCODES;               // 256 floats

    vq_wsum<<<KCODES / 256, 256, 0, stream>>>(weight, wsum);
    vq_main<<<NBLOCKS, BLOCK, 0, stream>>>(inp, weight, wsum,
                                           out_q, out_idx, block_loss);
    vq_loss_reduce<<<1, 256, 0, stream>>>(block_loss, out_loss);
}